// Round 5
// baseline (362.167 us; speedup 1.0000x reference)
//
#include <hip/hip_runtime.h>
#include <cstdint>
#include <cstddef>

typedef __bf16 bf16;
typedef __attribute__((ext_vector_type(8))) __bf16 bf16x8;
typedef __attribute__((ext_vector_type(4))) __bf16 bf16x4;
typedef __attribute__((ext_vector_type(4))) float f32x4;

#define ATT_SCALE 0.125f   // 1/sqrt(64)
#define NEG_BIG  -1000000000.0f

__device__ __forceinline__ f32x4 mfma16(bf16x8 a, bf16x8 b, f32x4 c) {
  return __builtin_amdgcn_mfma_f32_16x16x32_bf16(a, b, c, 0, 0, 0);
}

__device__ __forceinline__ void gload16(const bf16* g, bf16* l) {
  __builtin_amdgcn_global_load_lds((__attribute__((address_space(1))) void*)g,
                                   (__attribute__((address_space(3))) void*)l,
                                   16, 0, 0);
}

// ---------------- fused prep: all fp32->bf16 converts + RoPE table ----------------
__global__ __launch_bounds__(256) void prep_all(const float* __restrict__ hs,
                                                const float* __restrict__ Wq,
                                                const float* __restrict__ Wk,
                                                const float* __restrict__ Wv,
                                                const float* __restrict__ Wo,
                                                bf16* __restrict__ hs16, bf16* __restrict__ wq16,
                                                bf16* __restrict__ wk16, bf16* __restrict__ wv16,
                                                bf16* __restrict__ wo16,
                                                float* __restrict__ cosT, float* __restrict__ sinT) {
  int b = blockIdx.x, t = threadIdx.x;
  const float* src; bf16* dst; int i;
  if (b < 16384)      { src = hs; dst = hs16; i = b * 256 + t; }
  else if (b < 20480) { src = Wq; dst = wq16; i = (b - 16384) * 256 + t; }
  else if (b < 21504) { src = Wk; dst = wk16; i = (b - 20480) * 256 + t; }
  else if (b < 22528) { src = Wv; dst = wv16; i = (b - 21504) * 256 + t; }
  else if (b < 26624) { src = Wo; dst = wo16; i = (b - 22528) * 256 + t; }
  else {
    int idx = (b - 26624) * 256 + t;   // 8192*32
    int tt = idx >> 5, j = idx & 31;
    float inv = exp2f(-(float)j * (13.287712379549449f / 32.0f));
    float fr = (float)tt * inv;
    cosT[idx] = cosf(fr); sinT[idx] = sinf(fr);
    return;
  }
  float4 v = *((const float4*)src + i);
  bf16x4 o;
  o[0] = (bf16)v.x; o[1] = (bf16)v.y; o[2] = (bf16)v.z; o[3] = (bf16)v.w;
  *((bf16x4*)dst + i) = o;
}

// ---------------- 256x256 bf16 GEMM, 8-phase counted-vmcnt schedule ----------------
// C[m,n] = sum_k A[m,k]*B[n,k]. BK=64 (2 k-half planes of 32), 512 threads = 8 waves
// (2M x 4N), per-wave out 128x64 (acc[8][4]). LDS: As/Bs[2 buf][2 kh][256][32] = 128 KB.
// Iteration covers 2 K-tiles (buf0 then buf1), 8 phases of 16 MFMA each.
// Stage schedule (phase -> half): 1:A1(kt+1) 2:B1(kt+1) 3:A0(kt+2) 4:B0(kt+2)
//   5:A1(kt+2) 6:B1(kt+2) 7:A0(kt+3) 8:B0(kt+3); vmcnt(4) at even phases only.
// Every staged half's region was last read >=1 phase before issue (WAR-safe), and
// lands (FIFO vmcnt ledger) >=2 phases before first read.
// Chunk swizzle: within a 32-elem row, chunk l stored at l ^ ((r>>1)&3) (0 conflicts,
// verified round 4); applied on GLOBAL source, LDS linear, reads use same XOR.
template <int BSEL, int OUTF32, int ROPE>
__global__ __launch_bounds__(512, 2) void gemm256(const bf16* __restrict__ A,
                                                  const bf16* __restrict__ B0,
                                                  const bf16* __restrict__ B1,
                                                  const bf16* __restrict__ B2,
                                                  void* __restrict__ Cout,
                                                  const float* __restrict__ cosT,
                                                  const float* __restrict__ sinT,
                                                  int N, int K) {
  __shared__ bf16 As[2][2][8192];   // [buf][khalf][256 rows x 32 k]
  __shared__ bf16 Bs[2][2][8192];
  const int tid = threadIdx.x, lane = tid & 63, wid = tid >> 6;

  // XCD swizzle (grid counts are multiples of 8 -> bijective)
  const int nx = gridDim.x;
  int lin = blockIdx.x + nx * blockIdx.y;
  const int cpx = (nx * gridDim.y) >> 3;
  lin = (lin & 7) * cpx + (lin >> 3);
  const int m0 = (lin % nx) * 256, n0 = (lin / nx) * 256;

  const int wr = wid >> 2, wc = wid & 3;
  const int fr = lane & 15, g4 = lane >> 4;
  const int sw8 = (g4 ^ ((fr >> 1) & 3)) * 8;

  f32x4 acc[8][4] = {};

  auto brow = [&](int n) -> const bf16* {
    if (BSEL) {
      if (n < 2048) return B0 + (size_t)n * K;
      if (n < 2560) return B1 + (size_t)(n - 2048) * K;
      return B2 + (size_t)(n - 2560) * K;
    }
    return B0 + (size_t)n * K;
  };

  // staging sources: half-plane = 256 rows x 32 k; thread t inst j covers
  // elems (j*512+t)*8 -> row r=(j*512+t)>>2, chunk p=t&3, logical l=p^((r>>1)&3)
  const int r0 = tid >> 2, r1 = 128 + (tid >> 2);
  const int l0 = (tid & 3) ^ ((r0 >> 1) & 3);
  const int l1 = (tid & 3) ^ ((r1 >> 1) & 3);
  const bf16* aS0 = A + (size_t)(m0 + r0) * K + l0 * 8;
  const bf16* aS1 = A + (size_t)(m0 + r1) * K + l1 * 8;
  const bf16* bS0 = brow(n0 + r0) + l0 * 8;
  const bf16* bS1 = brow(n0 + r1) + l1 * 8;
  const int st0 = wid * 512;          // elems; HW adds lane*16B
  const int st1 = 4096 + wid * 512;

#define STAGE_A(BUF, KH, KT) { \
    gload16(aS0 + (KT) * 64 + (KH) * 32, &As[BUF][KH][0] + st0); \
    gload16(aS1 + (KT) * 64 + (KH) * 32, &As[BUF][KH][0] + st1); }
#define STAGE_B(BUF, KH, KT) { \
    gload16(bS0 + (KT) * 64 + (KH) * 32, &Bs[BUF][KH][0] + st0); \
    gload16(bS1 + (KT) * 64 + (KH) * 32, &Bs[BUF][KH][0] + st1); }
#define VMX {}
#define VM4 { asm volatile("s_waitcnt vmcnt(4)" ::: "memory"); }
#define VM0 { asm volatile("s_waitcnt vmcnt(0)" ::: "memory"); }

#define PHASE(BUF, KK, MH, LOADB, STG, VM) { \
    if (LOADB) { \
      _Pragma("unroll") for (int nf = 0; nf < 4; ++nf) \
        bfr[nf] = *(const bf16x8*)(&Bs[BUF][KK][0] + (wc * 64 + nf * 16 + fr) * 32 + sw8); \
    } \
    bf16x8 af[4]; \
    _Pragma("unroll") for (int mf = 0; mf < 4; ++mf) \
      af[mf] = *(const bf16x8*)(&As[BUF][KK][0] + (wr * 128 + (MH) * 64 + mf * 16 + fr) * 32 + sw8); \
    STG \
    __builtin_amdgcn_s_barrier(); \
    asm volatile("s_waitcnt lgkmcnt(0)" ::: "memory"); \
    __builtin_amdgcn_sched_barrier(0); \
    __builtin_amdgcn_s_setprio(1); \
    _Pragma("unroll") for (int mf = 0; mf < 4; ++mf) \
      _Pragma("unroll") for (int nf = 0; nf < 4; ++nf) \
        acc[(MH) * 4 + mf][nf] = mfma16(af[mf], bfr[nf], acc[(MH) * 4 + mf][nf]); \
    __builtin_amdgcn_s_setprio(0); \
    VM \
    __builtin_amdgcn_s_barrier(); \
    __builtin_amdgcn_sched_barrier(0); }

  // prologue: kt0 fully + kt1 k0-halves; vmcnt(4) -> kt0 landed
  STAGE_A(0, 0, 0); STAGE_B(0, 0, 0);
  STAGE_A(0, 1, 0); STAGE_B(0, 1, 0);
  STAGE_A(1, 0, 1); STAGE_B(1, 0, 1);
  asm volatile("s_waitcnt vmcnt(4)" ::: "memory");
  __builtin_amdgcn_s_barrier();

  const int NI = K >> 7;   // K/128 iterations, 2 K-tiles each
  for (int i = 0; i < NI - 1; ++i) {
    const int kt = 2 * i;
    bf16x8 bfr[4];
    PHASE(0, 0, 0, 1, STAGE_A(1, 1, kt + 1), VMX)
    PHASE(0, 0, 1, 0, STAGE_B(1, 1, kt + 1), VM4)
    PHASE(0, 1, 0, 1, STAGE_A(0, 0, kt + 2), VMX)
    PHASE(0, 1, 1, 0, STAGE_B(0, 0, kt + 2), VM4)
    PHASE(1, 0, 0, 1, STAGE_A(0, 1, kt + 2), VMX)
    PHASE(1, 0, 1, 0, STAGE_B(0, 1, kt + 2), VM4)
    PHASE(1, 1, 0, 1, STAGE_A(1, 0, kt + 3), VMX)
    PHASE(1, 1, 1, 0, STAGE_B(1, 0, kt + 3), VM4)
  }
  { // final iteration: only finish staging kt+1's k1 halves, drain by phase 4
    const int kt = 2 * (NI - 1);
    bf16x8 bfr[4];
    PHASE(0, 0, 0, 1, STAGE_A(1, 1, kt + 1), VMX)
    PHASE(0, 0, 1, 0, STAGE_B(1, 1, kt + 1), VM4)
    PHASE(0, 1, 0, 1, {}, VMX)
    PHASE(0, 1, 1, 0, {}, VM0)
    PHASE(1, 0, 0, 1, {}, VMX)
    PHASE(1, 0, 1, 0, {}, VMX)
    PHASE(1, 1, 0, 1, {}, VMX)
    PHASE(1, 1, 1, 0, {}, VMX)
  }
#undef PHASE
#undef STAGE_A
#undef STAGE_B

  // epilogue: acc[am] -> wave-tile row (am>>2)*64 + (am&3)*16
  const int fc = lane & 15, fr4 = (lane >> 4) * 4;
  if (ROPE && (n0 + wc * 64) < 2560) {
#pragma unroll
    for (int am = 0; am < 8; ++am)
#pragma unroll
      for (int i = 0; i < 4; ++i) {
        size_t row = (size_t)(m0 + wr * 128 + (am >> 2) * 64 + (am & 3) * 16 + fr4 + i);
        bf16* base = (bf16*)Cout + row * (size_t)N + n0 + wc * 64;
#pragma unroll
        for (int nf = 0; nf < 2; ++nf) {
          int j = nf * 16 + fc;
          float c = cosT[row * 32 + j], sn = sinT[row * 32 + j];
          float x1 = acc[am][nf][i], x2 = acc[am][nf + 2][i];
          base[j]      = (bf16)(x1 * c - x2 * sn);
          base[j + 32] = (bf16)(x2 * c + x1 * sn);
        }
      }
  } else {
#pragma unroll
    for (int am = 0; am < 8; ++am)
#pragma unroll
      for (int i = 0; i < 4; ++i) {
        size_t row = (size_t)(m0 + wr * 128 + (am >> 2) * 64 + (am & 3) * 16 + fr4 + i);
#pragma unroll
        for (int nf = 0; nf < 4; ++nf) {
          int col = n0 + wc * 64 + nf * 16 + fc;
          if (OUTF32)
            ((float*)Cout)[row * (size_t)N + col] = acc[am][nf][i];
          else
            ((bf16*)Cout)[row * (size_t)N + col] = (bf16)acc[am][nf][i];
        }
      }
  }
}

// ---------------- block-sparse attention, GQA-grouped, pipelined ----------------
// (unchanged from round 3 — validated)
__global__ __launch_bounds__(1024) void attn_sparse(const bf16* __restrict__ qkv,
                                                    bf16* __restrict__ attn) {
  const int iblk = blockIdx.x;
  const int kv = blockIdx.y;
  const int tid = threadIdx.x, lane = tid & 63, wid = tid >> 6;
  const int hloc = wid >> 2;
  const int h = kv * 4 + hloc;
  const int rg = wid & 3;

  __shared__ bf16 Ks[64 * 64];
  __shared__ bf16 Vt[2][64 * 72];
  __shared__ bf16 Ps[16 * 16 * 68];

  const int qcol = h * 64, kcol = 2048 + kv * 64, vcol = 2560 + kv * 64;
  const size_t trow0 = (size_t)iblk * 64;
  const int fr = lane & 15, g4 = lane >> 4, fk = g4 * 8, fr4 = g4 * 4;

  const bf16* qrow = qkv + (trow0 + rg * 16 + fr) * 3072 + qcol;
  bf16x8 bq0 = *(const bf16x8*)(qrow + fk);
  bf16x8 bq1 = *(const bf16x8*)(qrow + 32 + fk);

  float mrun = -INFINITY, lrun = 0.f;
  f32x4 acc[4] = {};

  const int kr = tid >> 3, ks = tid & 7;
  const int vu = tid & 511, vp = vu & 31, vd0 = (vu >> 5) * 4;
  const bool isK = (tid < 512);

  const int nsel = (iblk < 8) ? (iblk + 1) : 9;
  auto jof = [&](int js) { return (iblk < 8) ? js : ((js == 0) ? 0 : iblk - 8 + js); };

  {
    const size_t krow = (size_t)jof(0) * 64;
    if (isK) {
      const bf16* src = qkv + (krow + kr) * 3072 + kcol + ((ks ^ (kr & 7)) * 8);
      gload16(src, Ks + (tid >> 6) * 512);
    } else {
      const bf16* v0p = qkv + (krow + 2 * vp) * 3072 + vcol + vd0;
      uint64_t a = *(const uint64_t*)v0p;
      uint64_t b = *(const uint64_t*)(v0p + 3072);
#pragma unroll
      for (int e = 0; e < 4; ++e) {
        uint32_t w = (uint32_t)((a >> (16 * e)) & 0xFFFF) |
                     ((uint32_t)((b >> (16 * e)) & 0xFFFF) << 16);
        *(uint32_t*)(&Vt[0][0] + (vd0 + e) * 72 + 2 * vp) = w;
      }
    }
  }
  __syncthreads();

  for (int js = 0; js < nsel; ++js) {
    const int cur = js & 1;
    const int jblk = jof(js);
    const bool pre = (js + 1 < nsel);

    uint64_t va = 0, vb2 = 0;
    if (pre && !isK) {
      const bf16* v0p = qkv + ((size_t)jof(js + 1) * 64 + 2 * vp) * 3072 + vcol + vd0;
      va = *(const uint64_t*)v0p;
      vb2 = *(const uint64_t*)(v0p + 3072);
    }

    f32x4 s[4];
#pragma unroll
    for (int n = 0; n < 4; ++n) {
      const char* krowp = (const char*)Ks + (n * 16 + fr) * 128;
      bf16x8 kb0 = *(const bf16x8*)(krowp + ((g4 ^ (fr & 7)) << 4));
      bf16x8 kb1 = *(const bf16x8*)(krowp + (((4 + g4) ^ (fr & 7)) << 4));
      f32x4 z = {};
      z = mfma16(kb0, bq0, z);
      s[n] = mfma16(kb1, bq1, z);
    }

    __syncthreads();
    if (pre && isK) {
      const bf16* src = qkv + ((size_t)jof(js + 1) * 64 + kr) * 3072 + kcol +
                        ((ks ^ (kr & 7)) * 8);
      gload16(src, Ks + (tid >> 6) * 512);
    }

    const bool diag = (jblk == iblk);
    const int qr = rg * 16 + fr;
#pragma unroll
    for (int n = 0; n < 4; ++n)
#pragma unroll
      for (int i = 0; i < 4; ++i) {
        float sv = s[n][i] * ATT_SCALE;
        if (diag && (n * 16 + fr4 + i) > qr) sv = NEG_BIG;
        s[n][i] = sv;
      }

    float t0 = fmaxf(fmaxf(s[0][0], s[0][1]), fmaxf(s[0][2], s[0][3]));
    float t1 = fmaxf(fmaxf(s[1][0], s[1][1]), fmaxf(s[1][2], s[1][3]));
    float t2 = fmaxf(fmaxf(s[2][0], s[2][1]), fmaxf(s[2][2], s[2][3]));
    float t3 = fmaxf(fmaxf(s[3][0], s[3][1]), fmaxf(s[3][2], s[3][3]));
    float mx = fmaxf(fmaxf(t0, t1), fmaxf(t2, t3));
    mx = fmaxf(mx, __shfl_xor(mx, 16, 64));
    mx = fmaxf(mx, __shfl_xor(mx, 32, 64));
    float mnew = fmaxf(mrun, mx);
    float corr = __expf(mrun - mnew);
    mrun = mnew;
    float ps = 0.f;
#pragma unroll
    for (int n = 0; n < 4; ++n) {
      float p0 = __expf(s[n][0] - mnew), p1 = __expf(s[n][1] - mnew);
      float p2 = __expf(s[n][2] - mnew), p3 = __expf(s[n][3] - mnew);
      s[n][0] = p0; s[n][1] = p1; s[n][2] = p2; s[n][3] = p3;
      ps += (p0 + p1) + (p2 + p3);
    }
    ps += __shfl_xor(ps, 16, 64);
    ps += __shfl_xor(ps, 32, 64);
    lrun = lrun * corr + ps;

    float cq[4];
#pragma unroll
    for (int i = 0; i < 4; ++i) cq[i] = __shfl(corr, fr4 + i, 64);
#pragma unroll
    for (int n = 0; n < 4; ++n)
#pragma unroll
      for (int i = 0; i < 4; ++i) acc[n][i] *= cq[i];

    bf16* pbase = Ps + wid * (16 * 68);
#pragma unroll
    for (int n = 0; n < 4; ++n) {
      bf16x4 pk;
#pragma unroll
      for (int i = 0; i < 4; ++i) pk[i] = (bf16)s[n][i];
      *(bf16x4*)(pbase + fr * 68 + n * 16 + fr4) = pk;
    }
    bf16x8 pa0 = *(const bf16x8*)(pbase + fr * 68 + fk);
    bf16x8 pa1 = *(const bf16x8*)(pbase + fr * 68 + 32 + fk);

    if (pre && !isK) {
#pragma unroll
      for (int e = 0; e < 4; ++e) {
        uint32_t w = (uint32_t)((va >> (16 * e)) & 0xFFFF) |
                     ((uint32_t)((vb2 >> (16 * e)) & 0xFFFF) << 16);
        *(uint32_t*)(&Vt[cur ^ 1][0] + (vd0 + e) * 72 + 2 * vp) = w;
      }
    }

#pragma unroll
    for (int n = 0; n < 4; ++n) {
      bf16x8 vb0 = *(const bf16x8*)(&Vt[cur][0] + (n * 16 + fr) * 72 + fk);
      bf16x8 vb1 = *(const bf16x8*)(&Vt[cur][0] + (n * 16 + fr) * 72 + 32 + fk);
      acc[n] = mfma16(pa0, vb0, acc[n]);
      acc[n] = mfma16(pa1, vb1, acc[n]);
    }
    __syncthreads();
  }

  float lq[4];
#pragma unroll
  for (int i = 0; i < 4; ++i) lq[i] = __shfl(lrun, fr4 + i, 64);
#pragma unroll
  for (int i = 0; i < 4; ++i) {
    float rl = 1.0f / lq[i];
    size_t t = trow0 + rg * 16 + fr4 + i;
#pragma unroll
    for (int n = 0; n < 4; ++n)
      attn[t * 2048 + h * 64 + n * 16 + fr] = (bf16)(acc[n][i] * rl);
  }
}

// ---------------- launch ----------------
extern "C" void kernel_launch(void* const* d_in, const int* in_sizes, int n_in,
                              void* d_out, int out_size, void* d_ws, size_t ws_size,
                              hipStream_t stream) {
  (void)in_sizes; (void)n_in; (void)out_size; (void)ws_size;
  const float* hs = (const float*)d_in[0];
  const float* Wq = (const float*)d_in[1];
  const float* Wk = (const float*)d_in[2];
  const float* Wv = (const float*)d_in[3];
  const float* Wo = (const float*)d_in[4];
  float* out = (float*)d_out;

  char* ws = (char*)d_ws;
  bf16* hs16 = (bf16*)(ws + 0);              // 8192*2048*2  = 33554432
  bf16* qkv  = (bf16*)(ws + 33554432);       // 8192*3072*2  = 50331648
  bf16* attn = (bf16*)(ws + 83886080);       // 8192*2048*2  = 33554432
  bf16* wq16 = (bf16*)(ws + 117440512);      // 2048*2048*2  = 8388608
  bf16* wk16 = (bf16*)(ws + 125829120);      // 512*2048*2   = 2097152
  bf16* wv16 = (bf16*)(ws + 127926272);      // 512*2048*2   = 2097152
  bf16* wo16 = (bf16*)(ws + 130023424);      // 2048*2048*2  = 8388608
  float* cosT = (float*)(ws + 138412032);    // 8192*32*4    = 1048576
  float* sinT = (float*)(ws + 139460608);    // 8192*32*4    = 1048576

  prep_all<<<27648, 256, 0, stream>>>(hs, Wq, Wk, Wv, Wo,
                                      hs16, wq16, wk16, wv16, wo16, cosT, sinT);

  // QKV projection: M=8192, N=3072, K=2048, RoPE fused into epilogue
  gemm256<1, 0, 1><<<dim3(32, 12), 512, 0, stream>>>(hs16, wq16, wk16, wv16, qkv,
                                                     cosT, sinT, 3072, 2048);
  attn_sparse<<<dim3(128, 8), 1024, 0, stream>>>(qkv, attn);
  // O projection: M=8192, N=2048, K=2048, fp32 out
  gemm256<0, 1, 0><<<dim3(32, 8), 512, 0, stream>>>(attn, wo16, wo16, wo16, out,
                                                    nullptr, nullptr, 2048, 2048);
}

// Round 6
// 333.046 us; speedup vs baseline: 1.0874x; 1.0874x over previous
//
#include <hip/hip_runtime.h>
#include <cstdint>
#include <cstddef>

typedef __bf16 bf16;
typedef __attribute__((ext_vector_type(8))) __bf16 bf16x8;
typedef __attribute__((ext_vector_type(4))) __bf16 bf16x4;
typedef __attribute__((ext_vector_type(4))) float f32x4;

#define ATT_SCALE 0.125f   // 1/sqrt(64)
#define NEG_BIG  -1000000000.0f

__device__ __forceinline__ f32x4 mfma16(bf16x8 a, bf16x8 b, f32x4 c) {
  return __builtin_amdgcn_mfma_f32_16x16x32_bf16(a, b, c, 0, 0, 0);
}

__device__ __forceinline__ void gload16(const bf16* g, bf16* l) {
  __builtin_amdgcn_global_load_lds((__attribute__((address_space(1))) void*)g,
                                   (__attribute__((address_space(3))) void*)l,
                                   16, 0, 0);
}

// ---------------- fused prep: all fp32->bf16 converts + RoPE table ----------------
__global__ __launch_bounds__(256) void prep_all(const float* __restrict__ hs,
                                                const float* __restrict__ Wq,
                                                const float* __restrict__ Wk,
                                                const float* __restrict__ Wv,
                                                const float* __restrict__ Wo,
                                                bf16* __restrict__ hs16, bf16* __restrict__ wq16,
                                                bf16* __restrict__ wk16, bf16* __restrict__ wv16,
                                                bf16* __restrict__ wo16,
                                                float* __restrict__ cosT, float* __restrict__ sinT) {
  int b = blockIdx.x, t = threadIdx.x;
  const float* src; bf16* dst; int i;
  if (b < 16384)      { src = hs; dst = hs16; i = b * 256 + t; }
  else if (b < 20480) { src = Wq; dst = wq16; i = (b - 16384) * 256 + t; }
  else if (b < 21504) { src = Wk; dst = wk16; i = (b - 20480) * 256 + t; }
  else if (b < 22528) { src = Wv; dst = wv16; i = (b - 21504) * 256 + t; }
  else if (b < 26624) { src = Wo; dst = wo16; i = (b - 22528) * 256 + t; }
  else {
    int idx = (b - 26624) * 256 + t;   // 8192*32
    int tt = idx >> 5, j = idx & 31;
    float inv = exp2f(-(float)j * (13.287712379549449f / 32.0f));
    float fr = (float)tt * inv;
    cosT[idx] = cosf(fr); sinT[idx] = sinf(fr);
    return;
  }
  float4 v = *((const float4*)src + i);
  bf16x4 o;
  o[0] = (bf16)v.x; o[1] = (bf16)v.y; o[2] = (bf16)v.z; o[3] = (bf16)v.w;
  *((bf16x4*)dst + i) = o;
}

// ---------------- 256x256 bf16 GEMM, 8-phase counted-vmcnt schedule ----------------
// C[m,n] = sum_k A[m,k]*B[n,k]. BK=64 (2 k-half planes of 32), 512 threads = 8 waves
// (2M x 4N), per-wave out 128x64 (acc[8][4]). LDS: As/Bs[2 buf][2 kh][256][32] = 128 KB.
// NO XCD swizzle: natural dispatch round-robins m-panels across XCDs -> 4 A-panels
// (4 MB) per XCD L2 (round-4 evidence: 84 MB fetch vs 217-430 MB with swizzle).
// Stage schedule (phase -> half): 1:A1(kt+1) 2:B1(kt+1) 3:A0(kt+2) 4:B0(kt+2)
//   5:A1(kt+2) 6:B1(kt+2) 7:A0(kt+3) 8:B0(kt+3); vmcnt(4) at even phases only.
// Chunk swizzle: within a 32-elem row, chunk l stored at l ^ ((r>>1)&3) (0 conflicts);
// applied on GLOBAL source, LDS dest linear, reads use same XOR.
template <int BSEL, int OUTF32, int ROPE>
__global__ __launch_bounds__(512, 2) void gemm256(const bf16* __restrict__ A,
                                                  const bf16* __restrict__ B0,
                                                  const bf16* __restrict__ B1,
                                                  const bf16* __restrict__ B2,
                                                  void* __restrict__ Cout,
                                                  const float* __restrict__ cosT,
                                                  const float* __restrict__ sinT,
                                                  int N, int K) {
  __shared__ bf16 As[2][2][8192];   // [buf][khalf][256 rows x 32 k]
  __shared__ bf16 Bs[2][2][8192];
  const int tid = threadIdx.x, lane = tid & 63, wid = tid >> 6;
  const int m0 = blockIdx.x * 256, n0 = blockIdx.y * 256;

  const int wr = wid >> 2, wc = wid & 3;
  const int fr = lane & 15, g4 = lane >> 4;
  const int sw8 = (g4 ^ ((fr >> 1) & 3)) * 8;

  f32x4 acc[8][4] = {};

  auto brow = [&](int n) -> const bf16* {
    if (BSEL) {
      if (n < 2048) return B0 + (size_t)n * K;
      if (n < 2560) return B1 + (size_t)(n - 2048) * K;
      return B2 + (size_t)(n - 2560) * K;
    }
    return B0 + (size_t)n * K;
  };

  // staging sources: half-plane = 256 rows x 32 k; thread t inst j covers
  // elems (j*512+t)*8 -> row r=(j*512+t)>>2, chunk p=t&3, logical l=p^((r>>1)&3)
  const int r0 = tid >> 2, r1 = 128 + (tid >> 2);
  const int l0 = (tid & 3) ^ ((r0 >> 1) & 3);
  const int l1 = (tid & 3) ^ ((r1 >> 1) & 3);
  const bf16* aS0 = A + (size_t)(m0 + r0) * K + l0 * 8;
  const bf16* aS1 = A + (size_t)(m0 + r1) * K + l1 * 8;
  const bf16* bS0 = brow(n0 + r0) + l0 * 8;
  const bf16* bS1 = brow(n0 + r1) + l1 * 8;
  const int st0 = wid * 512;          // elems; HW adds lane*16B
  const int st1 = 4096 + wid * 512;

#define STAGE_A(BUF, KH, KT) { \
    gload16(aS0 + (KT) * 64 + (KH) * 32, &As[BUF][KH][0] + st0); \
    gload16(aS1 + (KT) * 64 + (KH) * 32, &As[BUF][KH][0] + st1); }
#define STAGE_B(BUF, KH, KT) { \
    gload16(bS0 + (KT) * 64 + (KH) * 32, &Bs[BUF][KH][0] + st0); \
    gload16(bS1 + (KT) * 64 + (KH) * 32, &Bs[BUF][KH][0] + st1); }
#define VMX {}
#define VM4 { asm volatile("s_waitcnt vmcnt(4)" ::: "memory"); }
#define VM0 { asm volatile("s_waitcnt vmcnt(0)" ::: "memory"); }

#define PHASE(BUF, KK, MH, LOADB, STG, VM) { \
    if (LOADB) { \
      _Pragma("unroll") for (int nf = 0; nf < 4; ++nf) \
        bfr[nf] = *(const bf16x8*)(&Bs[BUF][KK][0] + (wc * 64 + nf * 16 + fr) * 32 + sw8); \
    } \
    bf16x8 af[4]; \
    _Pragma("unroll") for (int mf = 0; mf < 4; ++mf) \
      af[mf] = *(const bf16x8*)(&As[BUF][KK][0] + (wr * 128 + (MH) * 64 + mf * 16 + fr) * 32 + sw8); \
    STG \
    __builtin_amdgcn_s_barrier(); \
    asm volatile("s_waitcnt lgkmcnt(0)" ::: "memory"); \
    __builtin_amdgcn_sched_barrier(0); \
    __builtin_amdgcn_s_setprio(1); \
    _Pragma("unroll") for (int mf = 0; mf < 4; ++mf) \
      _Pragma("unroll") for (int nf = 0; nf < 4; ++nf) \
        acc[(MH) * 4 + mf][nf] = mfma16(af[mf], bfr[nf], acc[(MH) * 4 + mf][nf]); \
    __builtin_amdgcn_s_setprio(0); \
    VM \
    __builtin_amdgcn_s_barrier(); \
    __builtin_amdgcn_sched_barrier(0); }

  // prologue: kt0 fully + kt1 k0-halves; vmcnt(4) -> kt0 landed
  STAGE_A(0, 0, 0); STAGE_B(0, 0, 0);
  STAGE_A(0, 1, 0); STAGE_B(0, 1, 0);
  STAGE_A(1, 0, 1); STAGE_B(1, 0, 1);
  asm volatile("s_waitcnt vmcnt(4)" ::: "memory");
  __builtin_amdgcn_s_barrier();

  const int NI = K >> 7;   // K/128 iterations, 2 K-tiles each
  for (int i = 0; i < NI - 1; ++i) {
    const int kt = 2 * i;
    bf16x8 bfr[4];
    PHASE(0, 0, 0, 1, STAGE_A(1, 1, kt + 1), VMX)
    PHASE(0, 0, 1, 0, STAGE_B(1, 1, kt + 1), VM4)
    PHASE(0, 1, 0, 1, STAGE_A(0, 0, kt + 2), VMX)
    PHASE(0, 1, 1, 0, STAGE_B(0, 0, kt + 2), VM4)
    PHASE(1, 0, 0, 1, STAGE_A(0, 1, kt + 2), VMX)
    PHASE(1, 0, 1, 0, STAGE_B(0, 1, kt + 2), VM4)
    PHASE(1, 1, 0, 1, STAGE_A(1, 0, kt + 3), VMX)
    PHASE(1, 1, 1, 0, STAGE_B(1, 0, kt + 3), VM4)
  }
  { // final iteration: only finish staging kt+1's k1 halves, drain by phase 4
    const int kt = 2 * (NI - 1);
    bf16x8 bfr[4];
    PHASE(0, 0, 0, 1, STAGE_A(1, 1, kt + 1), VMX)
    PHASE(0, 0, 1, 0, STAGE_B(1, 1, kt + 1), VM4)
    PHASE(0, 1, 0, 1, {}, VMX)
    PHASE(0, 1, 1, 0, {}, VM0)
    PHASE(1, 0, 0, 1, {}, VMX)
    PHASE(1, 0, 1, 0, {}, VMX)
    PHASE(1, 1, 0, 1, {}, VMX)
    PHASE(1, 1, 1, 0, {}, VMX)
  }
#undef PHASE
#undef STAGE_A
#undef STAGE_B

  // epilogue: acc[am] -> wave-tile row (am>>2)*64 + (am&3)*16
  const int fc = lane & 15, fr4 = (lane >> 4) * 4;
  if (ROPE && (n0 + wc * 64) < 2560) {
#pragma unroll
    for (int am = 0; am < 8; ++am)
#pragma unroll
      for (int i = 0; i < 4; ++i) {
        size_t row = (size_t)(m0 + wr * 128 + (am >> 2) * 64 + (am & 3) * 16 + fr4 + i);
        bf16* base = (bf16*)Cout + row * (size_t)N + n0 + wc * 64;
#pragma unroll
        for (int nf = 0; nf < 2; ++nf) {
          int j = nf * 16 + fc;
          float c = cosT[row * 32 + j], sn = sinT[row * 32 + j];
          float x1 = acc[am][nf][i], x2 = acc[am][nf + 2][i];
          base[j]      = (bf16)(x1 * c - x2 * sn);
          base[j + 32] = (bf16)(x2 * c + x1 * sn);
        }
      }
  } else {
#pragma unroll
    for (int am = 0; am < 8; ++am)
#pragma unroll
      for (int i = 0; i < 4; ++i) {
        size_t row = (size_t)(m0 + wr * 128 + (am >> 2) * 64 + (am & 3) * 16 + fr4 + i);
#pragma unroll
        for (int nf = 0; nf < 4; ++nf) {
          int col = n0 + wc * 64 + nf * 16 + fc;
          if (OUTF32)
            ((float*)Cout)[row * (size_t)N + col] = acc[am][nf][i];
          else
            ((bf16*)Cout)[row * (size_t)N + col] = (bf16)acc[am][nf][i];
        }
      }
  }
}

// ---------------- block-sparse attention, GQA-grouped, pipelined ----------------
// (unchanged from round 3 — validated)
__global__ __launch_bounds__(1024) void attn_sparse(const bf16* __restrict__ qkv,
                                                    bf16* __restrict__ attn) {
  const int iblk = blockIdx.x;
  const int kv = blockIdx.y;
  const int tid = threadIdx.x, lane = tid & 63, wid = tid >> 6;
  const int hloc = wid >> 2;
  const int h = kv * 4 + hloc;
  const int rg = wid & 3;

  __shared__ bf16 Ks[64 * 64];
  __shared__ bf16 Vt[2][64 * 72];
  __shared__ bf16 Ps[16 * 16 * 68];

  const int qcol = h * 64, kcol = 2048 + kv * 64, vcol = 2560 + kv * 64;
  const size_t trow0 = (size_t)iblk * 64;
  const int fr = lane & 15, g4 = lane >> 4, fk = g4 * 8, fr4 = g4 * 4;

  const bf16* qrow = qkv + (trow0 + rg * 16 + fr) * 3072 + qcol;
  bf16x8 bq0 = *(const bf16x8*)(qrow + fk);
  bf16x8 bq1 = *(const bf16x8*)(qrow + 32 + fk);

  float mrun = -INFINITY, lrun = 0.f;
  f32x4 acc[4] = {};

  const int kr = tid >> 3, ks = tid & 7;
  const int vu = tid & 511, vp = vu & 31, vd0 = (vu >> 5) * 4;
  const bool isK = (tid < 512);

  const int nsel = (iblk < 8) ? (iblk + 1) : 9;
  auto jof = [&](int js) { return (iblk < 8) ? js : ((js == 0) ? 0 : iblk - 8 + js); };

  {
    const size_t krow = (size_t)jof(0) * 64;
    if (isK) {
      const bf16* src = qkv + (krow + kr) * 3072 + kcol + ((ks ^ (kr & 7)) * 8);
      gload16(src, Ks + (tid >> 6) * 512);
    } else {
      const bf16* v0p = qkv + (krow + 2 * vp) * 3072 + vcol + vd0;
      uint64_t a = *(const uint64_t*)v0p;
      uint64_t b = *(const uint64_t*)(v0p + 3072);
#pragma unroll
      for (int e = 0; e < 4; ++e) {
        uint32_t w = (uint32_t)((a >> (16 * e)) & 0xFFFF) |
                     ((uint32_t)((b >> (16 * e)) & 0xFFFF) << 16);
        *(uint32_t*)(&Vt[0][0] + (vd0 + e) * 72 + 2 * vp) = w;
      }
    }
  }
  __syncthreads();

  for (int js = 0; js < nsel; ++js) {
    const int cur = js & 1;
    const int jblk = jof(js);
    const bool pre = (js + 1 < nsel);

    uint64_t va = 0, vb2 = 0;
    if (pre && !isK) {
      const bf16* v0p = qkv + ((size_t)jof(js + 1) * 64 + 2 * vp) * 3072 + vcol + vd0;
      va = *(const uint64_t*)v0p;
      vb2 = *(const uint64_t*)(v0p + 3072);
    }

    f32x4 s[4];
#pragma unroll
    for (int n = 0; n < 4; ++n) {
      const char* krowp = (const char*)Ks + (n * 16 + fr) * 128;
      bf16x8 kb0 = *(const bf16x8*)(krowp + ((g4 ^ (fr & 7)) << 4));
      bf16x8 kb1 = *(const bf16x8*)(krowp + (((4 + g4) ^ (fr & 7)) << 4));
      f32x4 z = {};
      z = mfma16(kb0, bq0, z);
      s[n] = mfma16(kb1, bq1, z);
    }

    __syncthreads();
    if (pre && isK) {
      const bf16* src = qkv + ((size_t)jof(js + 1) * 64 + kr) * 3072 + kcol +
                        ((ks ^ (kr & 7)) * 8);
      gload16(src, Ks + (tid >> 6) * 512);
    }

    const bool diag = (jblk == iblk);
    const int qr = rg * 16 + fr;
#pragma unroll
    for (int n = 0; n < 4; ++n)
#pragma unroll
      for (int i = 0; i < 4; ++i) {
        float sv = s[n][i] * ATT_SCALE;
        if (diag && (n * 16 + fr4 + i) > qr) sv = NEG_BIG;
        s[n][i] = sv;
      }

    float t0 = fmaxf(fmaxf(s[0][0], s[0][1]), fmaxf(s[0][2], s[0][3]));
    float t1 = fmaxf(fmaxf(s[1][0], s[1][1]), fmaxf(s[1][2], s[1][3]));
    float t2 = fmaxf(fmaxf(s[2][0], s[2][1]), fmaxf(s[2][2], s[2][3]));
    float t3 = fmaxf(fmaxf(s[3][0], s[3][1]), fmaxf(s[3][2], s[3][3]));
    float mx = fmaxf(fmaxf(t0, t1), fmaxf(t2, t3));
    mx = fmaxf(mx, __shfl_xor(mx, 16, 64));
    mx = fmaxf(mx, __shfl_xor(mx, 32, 64));
    float mnew = fmaxf(mrun, mx);
    float corr = __expf(mrun - mnew);
    mrun = mnew;
    float ps = 0.f;
#pragma unroll
    for (int n = 0; n < 4; ++n) {
      float p0 = __expf(s[n][0] - mnew), p1 = __expf(s[n][1] - mnew);
      float p2 = __expf(s[n][2] - mnew), p3 = __expf(s[n][3] - mnew);
      s[n][0] = p0; s[n][1] = p1; s[n][2] = p2; s[n][3] = p3;
      ps += (p0 + p1) + (p2 + p3);
    }
    ps += __shfl_xor(ps, 16, 64);
    ps += __shfl_xor(ps, 32, 64);
    lrun = lrun * corr + ps;

    float cq[4];
#pragma unroll
    for (int i = 0; i < 4; ++i) cq[i] = __shfl(corr, fr4 + i, 64);
#pragma unroll
    for (int n = 0; n < 4; ++n)
#pragma unroll
      for (int i = 0; i < 4; ++i) acc[n][i] *= cq[i];

    bf16* pbase = Ps + wid * (16 * 68);
#pragma unroll
    for (int n = 0; n < 4; ++n) {
      bf16x4 pk;
#pragma unroll
      for (int i = 0; i < 4; ++i) pk[i] = (bf16)s[n][i];
      *(bf16x4*)(pbase + fr * 68 + n * 16 + fr4) = pk;
    }
    bf16x8 pa0 = *(const bf16x8*)(pbase + fr * 68 + fk);
    bf16x8 pa1 = *(const bf16x8*)(pbase + fr * 68 + 32 + fk);

    if (pre && !isK) {
#pragma unroll
      for (int e = 0; e < 4; ++e) {
        uint32_t w = (uint32_t)((va >> (16 * e)) & 0xFFFF) |
                     ((uint32_t)((vb2 >> (16 * e)) & 0xFFFF) << 16);
        *(uint32_t*)(&Vt[cur ^ 1][0] + (vd0 + e) * 72 + 2 * vp) = w;
      }
    }

#pragma unroll
    for (int n = 0; n < 4; ++n) {
      bf16x8 vb0 = *(const bf16x8*)(&Vt[cur][0] + (n * 16 + fr) * 72 + fk);
      bf16x8 vb1 = *(const bf16x8*)(&Vt[cur][0] + (n * 16 + fr) * 72 + 32 + fk);
      acc[n] = mfma16(pa0, vb0, acc[n]);
      acc[n] = mfma16(pa1, vb1, acc[n]);
    }
    __syncthreads();
  }

  float lq[4];
#pragma unroll
  for (int i = 0; i < 4; ++i) lq[i] = __shfl(lrun, fr4 + i, 64);
#pragma unroll
  for (int i = 0; i < 4; ++i) {
    float rl = 1.0f / lq[i];
    size_t t = trow0 + rg * 16 + fr4 + i;
#pragma unroll
    for (int n = 0; n < 4; ++n)
      attn[t * 2048 + h * 64 + n * 16 + fr] = (bf16)(acc[n][i] * rl);
  }
}

// ---------------- launch ----------------
extern "C" void kernel_launch(void* const* d_in, const int* in_sizes, int n_in,
                              void* d_out, int out_size, void* d_ws, size_t ws_size,
                              hipStream_t stream) {
  (void)in_sizes; (void)n_in; (void)out_size; (void)ws_size;
  const float* hs = (const float*)d_in[0];
  const float* Wq = (const float*)d_in[1];
  const float* Wk = (const float*)d_in[2];
  const float* Wv = (const float*)d_in[3];
  const float* Wo = (const float*)d_in[4];
  float* out = (float*)d_out;

  char* ws = (char*)d_ws;
  bf16* hs16 = (bf16*)(ws + 0);              // 8192*2048*2  = 33554432
  bf16* qkv  = (bf16*)(ws + 33554432);       // 8192*3072*2  = 50331648
  bf16* attn = (bf16*)(ws + 83886080);       // 8192*2048*2  = 33554432
  bf16* wq16 = (bf16*)(ws + 117440512);      // 2048*2048*2  = 8388608
  bf16* wk16 = (bf16*)(ws + 125829120);      // 512*2048*2   = 2097152
  bf16* wv16 = (bf16*)(ws + 127926272);      // 512*2048*2   = 2097152
  bf16* wo16 = (bf16*)(ws + 130023424);      // 2048*2048*2  = 8388608
  float* cosT = (float*)(ws + 138412032);    // 8192*32*4    = 1048576
  float* sinT = (float*)(ws + 139460608);    // 8192*32*4    = 1048576

  prep_all<<<27648, 256, 0, stream>>>(hs, Wq, Wk, Wv, Wo,
                                      hs16, wq16, wk16, wv16, wo16, cosT, sinT);

  // QKV projection: M=8192, N=3072, K=2048, RoPE fused into epilogue
  gemm256<1, 0, 1><<<dim3(32, 12), 512, 0, stream>>>(hs16, wq16, wk16, wv16, qkv,
                                                     cosT, sinT, 3072, 2048);
  attn_sparse<<<dim3(128, 8), 1024, 0, stream>>>(qkv, attn);
  // O projection: M=8192, N=2048, K=2048, fp32 out
  gemm256<0, 1, 0><<<dim3(32, 8), 512, 0, stream>>>(attn, wo16, wo16, wo16, out,
                                                    nullptr, nullptr, 2048, 2048);
}